// Round 12
// baseline (112.498 us; speedup 1.0000x reference)
//
#include <hip/hip_runtime.h>
#include <math.h>

// Problem constants: B=2, L=256, D=256, H=4, DH=64.
// Output tuple: out (B,L,D)=131072 floats, then attn (B,H,L,L)=524288 floats.
//
// Algebra:
//  - qh . (pitch_rel @ pr_w^T)  ==  pitch_rel . (qh @ pr_w_headslice).
//  - pr_b / dr_b are j-constant logit offsets -> cancel in softmax -> dropped.
//  - 1/sqrt(DH) folded into qh.
//  - R11 post-mortem: stream at the ~3.6 TB/s read ceiling (74 us floor);
//    remaining cost was A-phase (k_mid + gaps ~25 us). R12: delete k_mid —
//    qpr/qdr rows (wave w = head w, prw slice read once per block) and qk4
//    (kh head slice) are computed in k_fused4's prologue (L2-bound, chip-
//    parallel ~10 us), then the verified NT-asm vmcnt(8) stream runs
//    unchanged. 2 launches total.

typedef float f4v __attribute__((ext_vector_type(4)));

#define SLD(dst, ptr)                                                     \
  asm volatile("global_load_dwordx4 %0, %1, off sc0 sc1 nt"               \
               : "=v"(dst)                                                \
               : "v"((unsigned long long)(const void*)(ptr))              \
               : "memory")

#define VW(n)                                             \
  asm volatile("s_waitcnt vmcnt(%0)" ::"i"(n) : "memory"); \
  __builtin_amdgcn_sched_barrier(0)

// ---------------------------------------------------------------- A: q/k/v projections + fcT
static __device__ void body_proj(
    int blk, const float* __restrict__ q, const float* __restrict__ k_,
    const float* __restrict__ v, const float* __restrict__ Wq, const float* __restrict__ Bq,
    const float* __restrict__ Wk, const float* __restrict__ Bk,
    const float* __restrict__ Wv, const float* __restrict__ Bv,
    float* __restrict__ qh, float* __restrict__ kh, float* __restrict__ vh) {
  int m = blk >> 5;
  int r = blk & 31;
  int b = r >> 4, it = (r >> 2) & 3, ot = r & 3;
  const float* X = (m == 0) ? q : (m == 1) ? k_ : v;
  const float* W = (m == 0) ? Wq : (m == 1) ? Wk : Wv;
  const float* Bs = (m == 0) ? Bq : (m == 1) ? Bk : Bv;
  float* OUT = (m == 0) ? qh : (m == 1) ? kh : vh;
  const float scale = (m == 0) ? 0.125f : 1.0f;

  __shared__ float xs[64][33];
  __shared__ float ws[64][33];
  int tid = threadIdx.x;
  int ti = tid >> 4, to = tid & 15;
  int lr = tid >> 2, lc = (tid & 3) * 8;
  float acc[4][4] = {};

  for (int k0 = 0; k0 < 256; k0 += 32) {
    float4 a0 = *(const float4*)(X + (size_t)(b * 256 + it * 64 + lr) * 256 + k0 + lc);
    float4 a1 = *(const float4*)(X + (size_t)(b * 256 + it * 64 + lr) * 256 + k0 + lc + 4);
    xs[lr][lc + 0] = a0.x; xs[lr][lc + 1] = a0.y; xs[lr][lc + 2] = a0.z; xs[lr][lc + 3] = a0.w;
    xs[lr][lc + 4] = a1.x; xs[lr][lc + 5] = a1.y; xs[lr][lc + 6] = a1.z; xs[lr][lc + 7] = a1.w;
    float4 w0 = *(const float4*)(W + (size_t)(ot * 64 + lr) * 256 + k0 + lc);
    float4 w1 = *(const float4*)(W + (size_t)(ot * 64 + lr) * 256 + k0 + lc + 4);
    ws[lr][lc + 0] = w0.x; ws[lr][lc + 1] = w0.y; ws[lr][lc + 2] = w0.z; ws[lr][lc + 3] = w0.w;
    ws[lr][lc + 4] = w1.x; ws[lr][lc + 5] = w1.y; ws[lr][lc + 6] = w1.z; ws[lr][lc + 7] = w1.w;
    __syncthreads();
#pragma unroll
    for (int kk = 0; kk < 32; ++kk) {
      float xv0 = xs[ti * 4 + 0][kk], xv1 = xs[ti * 4 + 1][kk];
      float xv2 = xs[ti * 4 + 2][kk], xv3 = xs[ti * 4 + 3][kk];
      float wv0 = ws[0 * 16 + to][kk], wv1 = ws[1 * 16 + to][kk];
      float wv2 = ws[2 * 16 + to][kk], wv3 = ws[3 * 16 + to][kk];
      acc[0][0] += xv0 * wv0; acc[0][1] += xv0 * wv1; acc[0][2] += xv0 * wv2; acc[0][3] += xv0 * wv3;
      acc[1][0] += xv1 * wv0; acc[1][1] += xv1 * wv1; acc[1][2] += xv1 * wv2; acc[1][3] += xv1 * wv3;
      acc[2][0] += xv2 * wv0; acc[2][1] += xv2 * wv1; acc[2][2] += xv2 * wv2; acc[2][3] += xv2 * wv3;
      acc[3][0] += xv3 * wv0; acc[3][1] += xv3 * wv1; acc[3][2] += xv3 * wv2; acc[3][3] += xv3 * wv3;
    }
    __syncthreads();
  }
#pragma unroll
  for (int ii = 0; ii < 4; ++ii)
#pragma unroll
    for (int oo = 0; oo < 4; ++oo) {
      int i = it * 64 + ti * 4 + ii;
      int dd = oo * 16 + to;
      OUT[(size_t)((b * 4 + ot) * 256 + i) * 64 + dd] = (acc[ii][oo] + Bs[ot * 64 + dd]) * scale;
    }
}

static __device__ void body_transpose(int blk, const float* __restrict__ in,
                                      float* __restrict__ out) {
  __shared__ float t[32][33];
  int bx = blk & 7, by = blk >> 3;
  int x = threadIdx.x & 31, y0 = threadIdx.x >> 5;
#pragma unroll
  for (int yy = 0; yy < 32; yy += 8)
    t[yy + y0][x] = in[(size_t)(by * 32 + yy + y0) * 256 + bx * 32 + x];
  __syncthreads();
#pragma unroll
  for (int yy = 0; yy < 32; yy += 8)
    out[(size_t)(bx * 32 + yy + y0) * 256 + by * 32 + x] = t[x][yy + y0];
}

__global__ __launch_bounds__(256) void k_proj(
    const float* __restrict__ q, const float* __restrict__ k_, const float* __restrict__ v,
    const float* __restrict__ Wq, const float* __restrict__ Bq,
    const float* __restrict__ Wk, const float* __restrict__ Bk,
    const float* __restrict__ Wv, const float* __restrict__ Bv,
    float* __restrict__ qh, float* __restrict__ kh, float* __restrict__ vh,
    const float* __restrict__ fcw, float* __restrict__ fcT) {
  int blk = blockIdx.x;
  if (blk < 96) body_proj(blk, q, k_, v, Wq, Bq, Wk, Bk, Wv, Bv, qh, kh, vh);
  else body_transpose(blk - 96, fcw, fcT);
}

// ---------------------------------------------------------------- B: fused prologue+stream+softmax+PV+fc
// One block per (b,i). Prologue (in-block, replaces k_mid): wave w stages
// qh[head w] row into LDS, builds qpr/qdr row for head w (prw/drw slice read
// once per block) into red scratch, computes qk4 (head w content logits) from
// kh; barrier; every thread grabs its qp/qd fragments; barrier. Then the
// R11-verified NT-asm vmcnt(8) stream, softmax, PV, fc.
__global__ __launch_bounds__(256, 2) void k_fused4(
    const float* __restrict__ pitch, const float* __restrict__ dur,
    const float* __restrict__ qh, const float* __restrict__ kh,
    const float* __restrict__ prw, const float* __restrict__ drw,
    const float* __restrict__ amask, const unsigned char* __restrict__ kpm,
    const float* __restrict__ vh, const float* __restrict__ fcT,
    const float* __restrict__ fcb, float* __restrict__ attn,
    float* __restrict__ out) {
  int bi = blockIdx.x;  // b*256 + i
  int b = bi >> 8, i = bi & 255;
  int tid = threadIdx.x, w = tid >> 6, l = tid & 63;
  int j0 = w * 64;

  __shared__ float red[4][4][4][65];  // 16.6 KB; prologue scratch then stream transpose
  __shared__ float logits[4][264];    // 4.2 KB; qh staging then logits
  __shared__ float pre[256];          // 1 KB

  // ---- prologue: qh staging (wave-local; one ds_write instr covers the wave)
  logits[w][l] = qh[((size_t)(b * 4 + w) * 256 + i) * 64 + l];

  // wave w -> qpr/qdr row for head w (e-slice 4l..4l+3); prw slice read once/block
  float* qprs = &red[0][0][0][0];  // [4][256]
  float* qdrs = qprs + 1024;       // [4][256]
  {
    const float* pw = prw + (size_t)(w * 64) * 256 + 4 * l;
    const float* dw = drw + (size_t)(w * 64) * 256 + 4 * l;
    float4 ap = make_float4(0.f, 0.f, 0.f, 0.f);
    float4 ad = make_float4(0.f, 0.f, 0.f, 0.f);
#pragma unroll 8
    for (int d = 0; d < 64; ++d) {
      float qv = logits[w][d];
      float4 pv = *(const float4*)(pw + d * 256);
      float4 dv = *(const float4*)(dw + d * 256);
      ap.x += qv * pv.x; ap.y += qv * pv.y; ap.z += qv * pv.z; ap.w += qv * pv.w;
      ad.x += qv * dv.x; ad.y += qv * dv.y; ad.z += qv * dv.z; ad.w += qv * dv.w;
    }
    *(float4*)&qprs[w * 256 + 4 * l] = ap;
    *(float4*)&qdrs[w * 256 + 4 * l] = ad;
  }

  // qk4: content logits for head w, j = 4l..4l+3 (qh scale already folded)
  float4 qk4;
  {
    const float* khb = kh + (size_t)((b * 4 + w) * 256) * 64;
    float a0 = 0.f, a1 = 0.f, a2 = 0.f, a3 = 0.f;
#pragma unroll 4
    for (int c = 0; c < 16; ++c) {
      float4 qv = *(const float4*)&logits[w][4 * c];
      float4 k0 = *(const float4*)(khb + (size_t)(4 * l + 0) * 64 + 4 * c);
      float4 k1 = *(const float4*)(khb + (size_t)(4 * l + 1) * 64 + 4 * c);
      float4 k2 = *(const float4*)(khb + (size_t)(4 * l + 2) * 64 + 4 * c);
      float4 k3 = *(const float4*)(khb + (size_t)(4 * l + 3) * 64 + 4 * c);
      a0 += k0.x * qv.x + k0.y * qv.y + k0.z * qv.z + k0.w * qv.w;
      a1 += k1.x * qv.x + k1.y * qv.y + k1.z * qv.z + k1.w * qv.w;
      a2 += k2.x * qv.x + k2.y * qv.y + k2.z * qv.z + k2.w * qv.w;
      a3 += k3.x * qv.x + k3.y * qv.y + k3.z * qv.z + k3.w * qv.w;
    }
    qk4 = make_float4(a0, a1, a2, a3);
  }

  // mask preloads
  float4 m4 = *(const float4*)(amask + (size_t)i * 256 + 4 * l);
  bool rowm = kpm[b * 256 + i] != 0;

  __syncthreads();
  // every thread grabs its qp/qd fragments (e-slice 4l..4l+3) for all heads
  float4 qp[4], qd[4];
#pragma unroll
  for (int h = 0; h < 4; ++h) {
    qp[h] = *(const float4*)&qprs[h * 256 + 4 * l];
    qd[h] = *(const float4*)&qdrs[h * 256 + 4 * l];
  }
  __syncthreads();  // red free for stream reuse; all outstanding vmem drained

  int p2 = l & 15, row_o = p2 >> 2, h_o = p2 & 3, sub = l >> 4;

  const float* pbase = pitch + ((size_t)bi * 256 + j0) * 256 + 4 * l;
  const float* dbase = dur + ((size_t)bi * 256 + j0) * 256 + 4 * l;

  f4v PA[4], DA[4], PB[4], DB[4];

#define ISSUE(PP, DD, g)                                  \
  {                                                       \
    _Pragma("unroll") for (int r = 0; r < 4; ++r) {       \
      SLD(PP[r], pbase + ((g) * 4 + r) * 256);            \
      SLD(DD[r], dbase + ((g) * 4 + r) * 256);            \
    }                                                     \
  }

#define COMPUTE(PP, DD, g)                                                        \
  {                                                                               \
    _Pragma("unroll") for (int r = 0; r < 4; ++r) {                               \
      red[w][r][0][l] = PP[r].x * qp[0].x + PP[r].y * qp[0].y + PP[r].z * qp[0].z \
                      + PP[r].w * qp[0].w + DD[r].x * qd[0].x + DD[r].y * qd[0].y \
                      + DD[r].z * qd[0].z + DD[r].w * qd[0].w;                    \
      red[w][r][1][l] = PP[r].x * qp[1].x + PP[r].y * qp[1].y + PP[r].z * qp[1].z \
                      + PP[r].w * qp[1].w + DD[r].x * qd[1].x + DD[r].y * qd[1].y \
                      + DD[r].z * qd[1].z + DD[r].w * qd[1].w;                    \
      red[w][r][2][l] = PP[r].x * qp[2].x + PP[r].y * qp[2].y + PP[r].z * qp[2].z \
                      + PP[r].w * qp[2].w + DD[r].x * qd[2].x + DD[r].y * qd[2].y \
                      + DD[r].z * qd[2].z + DD[r].w * qd[2].w;                    \
      red[w][r][3][l] = PP[r].x * qp[3].x + PP[r].y * qp[3].y + PP[r].z * qp[3].z \
                      + PP[r].w * qp[3].w + DD[r].x * qd[3].x + DD[r].y * qd[3].y \
                      + DD[r].z * qd[3].z + DD[r].w * qd[3].w;                    \
    }                                                                             \
    float x = 0.f;                                                                \
    {                                                                             \
      const float* rr = &red[w][row_o][h_o][sub * 16];                            \
      _Pragma("unroll") for (int c = 0; c < 16; ++c) x += rr[c];                  \
    }                                                                             \
    x += __shfl_xor(x, 16);                                                       \
    x += __shfl_xor(x, 32);                                                       \
    if (l < 16) logits[h_o][j0 + (g) * 4 + row_o] = x;                            \
  }

  ISSUE(PA, DA, 0);
  ISSUE(PB, DB, 1);
#pragma unroll
  for (int gg = 0; gg < 8; ++gg) {
    VW(8);
    COMPUTE(PA, DA, 2 * gg);
    if (gg < 7) ISSUE(PA, DA, 2 * gg + 2);
    if (gg < 7) {
      VW(8);
    } else {
      VW(0);
    }
    COMPUTE(PB, DB, 2 * gg + 1);
    if (gg < 7) ISSUE(PB, DB, 2 * gg + 3);
  }
#undef ISSUE
#undef COMPUTE
  __syncthreads();

  // ---- softmax: wave w owns head w; lane l handles j = 4l..4l+3
  float* lrow = &logits[w][0];
  float* qrow = attn + (size_t)((b * 4 + w) * 256 + i) * 256;
  float4 bv = *(float4*)(lrow + 4 * l);
  float v0 = (rowm || m4.x != 0.f) ? -9e15f : qk4.x + bv.x;
  float v1 = (rowm || m4.y != 0.f) ? -9e15f : qk4.y + bv.y;
  float v2 = (rowm || m4.z != 0.f) ? -9e15f : qk4.z + bv.z;
  float v3 = (rowm || m4.w != 0.f) ? -9e15f : qk4.w + bv.w;

  float mx = fmaxf(fmaxf(v0, v1), fmaxf(v2, v3));
#pragma unroll
  for (int m = 1; m <= 32; m <<= 1) mx = fmaxf(mx, __shfl_xor(mx, m));
  float e0 = __expf(v0 - mx), e1 = __expf(v1 - mx);
  float e2 = __expf(v2 - mx), e3 = __expf(v3 - mx);
  float sm = e0 + e1 + e2 + e3;
#pragma unroll
  for (int m = 1; m <= 32; m <<= 1) sm += __shfl_xor(sm, m);
  float inv = 1.0f / sm;
  float4 a4 = make_float4(e0 * inv, e1 * inv, e2 * inv, e3 * inv);
  *(float4*)(qrow + 4 * l) = a4;   // graded attn output
  *(float4*)(lrow + 4 * l) = a4;   // in-LDS for PV (same wave -> no barrier)

  // ---- PV: thread (h=w, l): out-dim l of head w
  float acc = 0.f;
  const float* vbase = vh + (size_t)(b * 4 + w) * 256 * 64 + l;
#pragma unroll 4
  for (int jj = 0; jj < 256; ++jj) acc += lrow[jj] * vbase[(size_t)jj * 64];
  pre[tid] = acc;
  __syncthreads();

  // ---- fc
  float acc2 = fcb[tid];
#pragma unroll 4
  for (int c = 0; c < 256; ++c) acc2 += pre[c] * fcT[(size_t)c * 256 + tid];
  out[(size_t)(b * 256 + i) * 256 + tid] = acc2;
}

// ---------------------------------------------------------------- launcher
extern "C" void kernel_launch(void* const* d_in, const int* in_sizes, int n_in,
                              void* d_out, int out_size, void* d_ws, size_t ws_size,
                              hipStream_t stream) {
  (void)in_sizes; (void)n_in; (void)out_size; (void)ws_size;
  const float* q = (const float*)d_in[0];
  const float* k = (const float*)d_in[1];
  const float* v = (const float*)d_in[2];
  const float* amask = (const float*)d_in[3];
  const unsigned char* kpm = (const unsigned char*)d_in[4];
  const float* pitch = (const float*)d_in[5];
  const float* dur = (const float*)d_in[6];
  const float* Wq = (const float*)d_in[7];
  const float* Bq = (const float*)d_in[8];
  const float* Wk = (const float*)d_in[9];
  const float* Bk = (const float*)d_in[10];
  const float* Wv = (const float*)d_in[11];
  const float* Bv = (const float*)d_in[12];
  const float* fcw = (const float*)d_in[13];
  const float* fcb = (const float*)d_in[14];
  const float* prw = (const float*)d_in[15];
  const float* drw = (const float*)d_in[17];
  // pr_b (16) / dr_b (18) intentionally unused: j-constant logit offsets cancel in softmax.

  float* out = (float*)d_out;
  float* attn = out + 2 * 256 * 256;  // 131072

  float* wsf = (float*)d_ws;
  float* qh = wsf;              // 131072
  float* kh = qh + 131072;      // 131072
  float* vh = kh + 131072;      // 131072
  float* fcT = vh + 131072;     // 65536   (total ~1.8 MB)

  k_proj<<<160, 256, 0, stream>>>(q, k, v, Wq, Bq, Wk, Bk, Wv, Bv, qh, kh, vh, fcw, fcT);
  k_fused4<<<512, 256, 0, stream>>>(pitch, dur, qh, kh, prw, drw, amask, kpm, vh, fcT,
                                    fcb, attn, out);
}

// Round 13
// 106.656 us; speedup vs baseline: 1.0548x; 1.0548x over previous
//
#include <hip/hip_runtime.h>
#include <math.h>

// Problem constants: B=2, L=256, D=256, H=4, DH=64.
// Output tuple: out (B,L,D)=131072 floats, then attn (B,H,L,L)=524288 floats.
//
// Algebra:
//  - qh . (pitch_rel @ pr_w^T)  ==  pitch_rel . (qh @ pr_w_headslice)  -> precompute qpr.
//  - pr_b / dr_b are j-constant logit offsets -> cancel in softmax -> dropped.
//  - 1/sqrt(DH) folded into qh.
//  - R12 post-mortem: in-kernel prologue re-read prw/drw per block = 268 MB of
//    L2 traffic through the same CU load path as the stream -> +15 us/block.
//    Reverted to the R11 champion (108.1 us): separate k_mid computes qpr/qdr/qk
//    once; k_fused3 streams pitch/dur with NT-asm vmcnt(8) pipeline at the
//    measured ~3.6 TB/s read ceiling, then in-block softmax+PV+fc.
//    Only change vs R11: fcT transpose moved into k_proj (no qh/kh dependence).

typedef float f4v __attribute__((ext_vector_type(4)));

#define SLD(dst, ptr)                                                     \
  asm volatile("global_load_dwordx4 %0, %1, off sc0 sc1 nt"               \
               : "=v"(dst)                                                \
               : "v"((unsigned long long)(const void*)(ptr))              \
               : "memory")

#define VW(n)                                             \
  asm volatile("s_waitcnt vmcnt(%0)" ::"i"(n) : "memory"); \
  __builtin_amdgcn_sched_barrier(0)

// ---------------------------------------------------------------- A1: q/k/v projections + fcT
static __device__ void body_proj(
    int blk, const float* __restrict__ q, const float* __restrict__ k_,
    const float* __restrict__ v, const float* __restrict__ Wq, const float* __restrict__ Bq,
    const float* __restrict__ Wk, const float* __restrict__ Bk,
    const float* __restrict__ Wv, const float* __restrict__ Bv,
    float* __restrict__ qh, float* __restrict__ kh, float* __restrict__ vh) {
  int m = blk >> 5;
  int r = blk & 31;
  int b = r >> 4, it = (r >> 2) & 3, ot = r & 3;
  const float* X = (m == 0) ? q : (m == 1) ? k_ : v;
  const float* W = (m == 0) ? Wq : (m == 1) ? Wk : Wv;
  const float* Bs = (m == 0) ? Bq : (m == 1) ? Bk : Bv;
  float* OUT = (m == 0) ? qh : (m == 1) ? kh : vh;
  const float scale = (m == 0) ? 0.125f : 1.0f;

  __shared__ float xs[64][33];
  __shared__ float ws[64][33];
  int tid = threadIdx.x;
  int ti = tid >> 4, to = tid & 15;
  int lr = tid >> 2, lc = (tid & 3) * 8;
  float acc[4][4] = {};

  for (int k0 = 0; k0 < 256; k0 += 32) {
    float4 a0 = *(const float4*)(X + (size_t)(b * 256 + it * 64 + lr) * 256 + k0 + lc);
    float4 a1 = *(const float4*)(X + (size_t)(b * 256 + it * 64 + lr) * 256 + k0 + lc + 4);
    xs[lr][lc + 0] = a0.x; xs[lr][lc + 1] = a0.y; xs[lr][lc + 2] = a0.z; xs[lr][lc + 3] = a0.w;
    xs[lr][lc + 4] = a1.x; xs[lr][lc + 5] = a1.y; xs[lr][lc + 6] = a1.z; xs[lr][lc + 7] = a1.w;
    float4 w0 = *(const float4*)(W + (size_t)(ot * 64 + lr) * 256 + k0 + lc);
    float4 w1 = *(const float4*)(W + (size_t)(ot * 64 + lr) * 256 + k0 + lc + 4);
    ws[lr][lc + 0] = w0.x; ws[lr][lc + 1] = w0.y; ws[lr][lc + 2] = w0.z; ws[lr][lc + 3] = w0.w;
    ws[lr][lc + 4] = w1.x; ws[lr][lc + 5] = w1.y; ws[lr][lc + 6] = w1.z; ws[lr][lc + 7] = w1.w;
    __syncthreads();
#pragma unroll
    for (int kk = 0; kk < 32; ++kk) {
      float xv0 = xs[ti * 4 + 0][kk], xv1 = xs[ti * 4 + 1][kk];
      float xv2 = xs[ti * 4 + 2][kk], xv3 = xs[ti * 4 + 3][kk];
      float wv0 = ws[0 * 16 + to][kk], wv1 = ws[1 * 16 + to][kk];
      float wv2 = ws[2 * 16 + to][kk], wv3 = ws[3 * 16 + to][kk];
      acc[0][0] += xv0 * wv0; acc[0][1] += xv0 * wv1; acc[0][2] += xv0 * wv2; acc[0][3] += xv0 * wv3;
      acc[1][0] += xv1 * wv0; acc[1][1] += xv1 * wv1; acc[1][2] += xv1 * wv2; acc[1][3] += xv1 * wv3;
      acc[2][0] += xv2 * wv0; acc[2][1] += xv2 * wv1; acc[2][2] += xv2 * wv2; acc[2][3] += xv2 * wv3;
      acc[3][0] += xv3 * wv0; acc[3][1] += xv3 * wv1; acc[3][2] += xv3 * wv2; acc[3][3] += xv3 * wv3;
    }
    __syncthreads();
  }
#pragma unroll
  for (int ii = 0; ii < 4; ++ii)
#pragma unroll
    for (int oo = 0; oo < 4; ++oo) {
      int i = it * 64 + ti * 4 + ii;
      int dd = oo * 16 + to;
      OUT[(size_t)((b * 4 + ot) * 256 + i) * 64 + dd] = (acc[ii][oo] + Bs[ot * 64 + dd]) * scale;
    }
}

static __device__ void body_transpose(int blk, const float* __restrict__ in,
                                      float* __restrict__ out) {
  __shared__ float t[32][33];
  int bx = blk & 7, by = blk >> 3;
  int x = threadIdx.x & 31, y0 = threadIdx.x >> 5;
#pragma unroll
  for (int yy = 0; yy < 32; yy += 8)
    t[yy + y0][x] = in[(size_t)(by * 32 + yy + y0) * 256 + bx * 32 + x];
  __syncthreads();
#pragma unroll
  for (int yy = 0; yy < 32; yy += 8)
    out[(size_t)(bx * 32 + yy + y0) * 256 + by * 32 + x] = t[x][yy + y0];
}

__global__ __launch_bounds__(256) void k_proj(
    const float* __restrict__ q, const float* __restrict__ k_, const float* __restrict__ v,
    const float* __restrict__ Wq, const float* __restrict__ Bq,
    const float* __restrict__ Wk, const float* __restrict__ Bk,
    const float* __restrict__ Wv, const float* __restrict__ Bv,
    float* __restrict__ qh, float* __restrict__ kh, float* __restrict__ vh,
    const float* __restrict__ fcw, float* __restrict__ fcT) {
  int blk = blockIdx.x;
  if (blk < 96) body_proj(blk, q, k_, v, Wq, Bq, Wk, Bk, Wv, Bv, qh, kh, vh);
  else body_transpose(blk - 96, fcw, fcT);
}

// ---------------------------------------------------------------- A2: qpr/qdr + qk (k_mid)
static __device__ void body_qprdr(int blk, const float* __restrict__ qh,
                                  const float* __restrict__ prw, const float* __restrict__ drw,
                                  float* __restrict__ qpr, float* __restrict__ qdr) {
  int t = blk >> 7;
  int r2 = blk & 127;
  int rt = r2 >> 2, et = r2 & 3;
  const float* W = t ? drw : prw;
  float* OUT = t ? qdr : qpr;
  int h = (rt >> 2) & 3;

  __shared__ float xs[64][33];
  __shared__ float ws2[32][64];
  int tid = threadIdx.x;
  int ti = tid >> 4, to = tid & 15;
  float acc[4][4] = {};

  for (int k0 = 0; k0 < 64; k0 += 32) {
    int lr = tid >> 2, lc = (tid & 3) * 8;
    float4 a0 = *(const float4*)(qh + (size_t)(rt * 64 + lr) * 64 + k0 + lc);
    float4 a1 = *(const float4*)(qh + (size_t)(rt * 64 + lr) * 64 + k0 + lc + 4);
    xs[lr][lc + 0] = a0.x; xs[lr][lc + 1] = a0.y; xs[lr][lc + 2] = a0.z; xs[lr][lc + 3] = a0.w;
    xs[lr][lc + 4] = a1.x; xs[lr][lc + 5] = a1.y; xs[lr][lc + 6] = a1.z; xs[lr][lc + 7] = a1.w;
    int wr = tid >> 3, wc = (tid & 7) * 8;
    float4 w0 = *(const float4*)(W + (size_t)(h * 64 + k0 + wr) * 256 + et * 64 + wc);
    float4 w1 = *(const float4*)(W + (size_t)(h * 64 + k0 + wr) * 256 + et * 64 + wc + 4);
    ws2[wr][wc + 0] = w0.x; ws2[wr][wc + 1] = w0.y; ws2[wr][wc + 2] = w0.z; ws2[wr][wc + 3] = w0.w;
    ws2[wr][wc + 4] = w1.x; ws2[wr][wc + 5] = w1.y; ws2[wr][wc + 6] = w1.z; ws2[wr][wc + 7] = w1.w;
    __syncthreads();
#pragma unroll
    for (int kk = 0; kk < 32; ++kk) {
      float xv0 = xs[ti * 4 + 0][kk], xv1 = xs[ti * 4 + 1][kk];
      float xv2 = xs[ti * 4 + 2][kk], xv3 = xs[ti * 4 + 3][kk];
      float wv0 = ws2[kk][0 * 16 + to], wv1 = ws2[kk][1 * 16 + to];
      float wv2 = ws2[kk][2 * 16 + to], wv3 = ws2[kk][3 * 16 + to];
      acc[0][0] += xv0 * wv0; acc[0][1] += xv0 * wv1; acc[0][2] += xv0 * wv2; acc[0][3] += xv0 * wv3;
      acc[1][0] += xv1 * wv0; acc[1][1] += xv1 * wv1; acc[1][2] += xv1 * wv2; acc[1][3] += xv1 * wv3;
      acc[2][0] += xv2 * wv0; acc[2][1] += xv2 * wv1; acc[2][2] += xv2 * wv2; acc[2][3] += xv2 * wv3;
      acc[3][0] += xv3 * wv0; acc[3][1] += xv3 * wv1; acc[3][2] += xv3 * wv2; acc[3][3] += xv3 * wv3;
    }
    __syncthreads();
  }
#pragma unroll
  for (int ii = 0; ii < 4; ++ii)
#pragma unroll
    for (int oo = 0; oo < 4; ++oo)
      OUT[(size_t)(rt * 64 + ti * 4 + ii) * 256 + et * 64 + oo * 16 + to] = acc[ii][oo];
}

static __device__ void body_qk(int blk, const float* __restrict__ qh,
                               const float* __restrict__ kh, float* __restrict__ qk) {
  int bh = blk >> 4, it = (blk >> 2) & 3, jt = blk & 3;
  __shared__ float xs[64][33];
  __shared__ float ys[64][33];
  int tid = threadIdx.x;
  int ti = tid >> 4, to = tid & 15;
  float acc[4][4] = {};

  for (int k0 = 0; k0 < 64; k0 += 32) {
    int lr = tid >> 2, lc = (tid & 3) * 8;
    float4 a0 = *(const float4*)(qh + (size_t)(bh * 256 + it * 64 + lr) * 64 + k0 + lc);
    float4 a1 = *(const float4*)(qh + (size_t)(bh * 256 + it * 64 + lr) * 64 + k0 + lc + 4);
    xs[lr][lc + 0] = a0.x; xs[lr][lc + 1] = a0.y; xs[lr][lc + 2] = a0.z; xs[lr][lc + 3] = a0.w;
    xs[lr][lc + 4] = a1.x; xs[lr][lc + 5] = a1.y; xs[lr][lc + 6] = a1.z; xs[lr][lc + 7] = a1.w;
    float4 b0 = *(const float4*)(kh + (size_t)(bh * 256 + jt * 64 + lr) * 64 + k0 + lc);
    float4 b1 = *(const float4*)(kh + (size_t)(bh * 256 + jt * 64 + lr) * 64 + k0 + lc + 4);
    ys[lr][lc + 0] = b0.x; ys[lr][lc + 1] = b0.y; ys[lr][lc + 2] = b0.z; ys[lr][lc + 3] = b0.w;
    ys[lr][lc + 4] = b1.x; ys[lr][lc + 5] = b1.y; ys[lr][lc + 6] = b1.z; ys[lr][lc + 7] = b1.w;
    __syncthreads();
#pragma unroll
    for (int kk = 0; kk < 32; ++kk) {
      float xv0 = xs[ti * 4 + 0][kk], xv1 = xs[ti * 4 + 1][kk];
      float xv2 = xs[ti * 4 + 2][kk], xv3 = xs[ti * 4 + 3][kk];
      float wv0 = ys[0 * 16 + to][kk], wv1 = ys[1 * 16 + to][kk];
      float wv2 = ys[2 * 16 + to][kk], wv3 = ys[3 * 16 + to][kk];
      acc[0][0] += xv0 * wv0; acc[0][1] += xv0 * wv1; acc[0][2] += xv0 * wv2; acc[0][3] += xv0 * wv3;
      acc[1][0] += xv1 * wv0; acc[1][1] += xv1 * wv1; acc[1][2] += xv1 * wv2; acc[1][3] += xv1 * wv3;
      acc[2][0] += xv2 * wv0; acc[2][1] += xv2 * wv1; acc[2][2] += xv2 * wv2; acc[2][3] += xv2 * wv3;
      acc[3][0] += xv3 * wv0; acc[3][1] += xv3 * wv1; acc[3][2] += xv3 * wv2; acc[3][3] += xv3 * wv3;
    }
    __syncthreads();
  }
#pragma unroll
  for (int ii = 0; ii < 4; ++ii)
#pragma unroll
    for (int jj = 0; jj < 4; ++jj)
      qk[(size_t)(bh * 256 + it * 64 + ti * 4 + ii) * 256 + jt * 64 + jj * 16 + to] = acc[ii][jj];
}

__global__ __launch_bounds__(256) void k_mid(
    const float* __restrict__ qh, const float* __restrict__ kh,
    const float* __restrict__ prw, const float* __restrict__ drw,
    float* __restrict__ qpr, float* __restrict__ qdr, float* __restrict__ qk) {
  int blk = blockIdx.x;
  if (blk < 256) body_qprdr(blk, qh, prw, drw, qpr, qdr);
  else body_qk(blk - 256, qh, kh, qk);
}

// ---------------------------------------------------------------- B: fused stream+softmax+PV+fc
// One block per (b,i). Wave w streams j in [w*64, w*64+64) as 16 groups of 4
// rows with the NT-asm vmcnt(8) 2-group pipeline (measured at the ~3.6 TB/s
// chip read ceiling); logits to LDS; in-block softmax (wave w = head w), PV, fc.
__global__ __launch_bounds__(256, 4) void k_fused3(
    const float* __restrict__ pitch, const float* __restrict__ dur,
    const float* __restrict__ qpr, const float* __restrict__ qdr,
    const float* __restrict__ amask, const unsigned char* __restrict__ kpm,
    const float* __restrict__ vh, const float* __restrict__ fcT,
    const float* __restrict__ fcb, float* __restrict__ attn,
    float* __restrict__ out) {
  int bi = blockIdx.x;  // b*256 + i
  int b = bi >> 8, i = bi & 255;
  int tid = threadIdx.x, w = tid >> 6, l = tid & 63;
  int j0 = w * 64;

  __shared__ float red[4][4][4][65];  // 16.6 KB, per-wave regions
  __shared__ float logits[4][264];    // 4.2 KB, padded rows
  __shared__ float pre[256];          // 1 KB

  float4 qp[4], qd[4];
#pragma unroll
  for (int h = 0; h < 4; ++h) {
    qp[h] = *(const float4*)(qpr + (size_t)((b * 4 + h) * 256 + i) * 256 + 4 * l);
    qd[h] = *(const float4*)(qdr + (size_t)((b * 4 + h) * 256 + i) * 256 + 4 * l);
  }

  float* qrow = attn + (size_t)((b * 4 + w) * 256 + i) * 256;
  float4 qk4 = *(const float4*)(qrow + 4 * l);
  float4 m4 = *(const float4*)(amask + (size_t)i * 256 + 4 * l);
  bool rowm = kpm[b * 256 + i] != 0;

  int p2 = l & 15, row_o = p2 >> 2, h_o = p2 & 3, sub = l >> 4;

  const float* pbase = pitch + ((size_t)bi * 256 + j0) * 256 + 4 * l;
  const float* dbase = dur + ((size_t)bi * 256 + j0) * 256 + 4 * l;

  asm volatile("s_waitcnt vmcnt(0)" ::: "memory");

  f4v PA[4], DA[4], PB[4], DB[4];

#define ISSUE(PP, DD, g)                                  \
  {                                                       \
    _Pragma("unroll") for (int r = 0; r < 4; ++r) {       \
      SLD(PP[r], pbase + ((g) * 4 + r) * 256);            \
      SLD(DD[r], dbase + ((g) * 4 + r) * 256);            \
    }                                                     \
  }

#define COMPUTE(PP, DD, g)                                                        \
  {                                                                               \
    _Pragma("unroll") for (int r = 0; r < 4; ++r) {                               \
      red[w][r][0][l] = PP[r].x * qp[0].x + PP[r].y * qp[0].y + PP[r].z * qp[0].z \
                      + PP[r].w * qp[0].w + DD[r].x * qd[0].x + DD[r].y * qd[0].y \
                      + DD[r].z * qd[0].z + DD[r].w * qd[0].w;                    \
      red[w][r][1][l] = PP[r].x * qp[1].x + PP[r].y * qp[1].y + PP[r].z * qp[1].z \
                      + PP[r].w * qp[1].w + DD[r].x * qd[1].x + DD[r].y * qd[1].y \
                      + DD[r].z * qd[1].z + DD[r].w * qd[1].w;                    \
      red[w][r][2][l] = PP[r].x * qp[2].x + PP[r].y * qp[2].y + PP[r].z * qp[2].z \
                      + PP[r].w * qp[2].w + DD[r].x * qd[2].x + DD[r].y * qd[2].y \
                      + DD[r].z * qd[2].z + DD[r].w * qd[2].w;                    \
      red[w][r][3][l] = PP[r].x * qp[3].x + PP[r].y * qp[3].y + PP[r].z * qp[3].z \
                      + PP[r].w * qp[3].w + DD[r].x * qd[3].x + DD[r].y * qd[3].y \
                      + DD[r].z * qd[3].z + DD[r].w * qd[3].w;                    \
    }                                                                             \
    float x = 0.f;                                                                \
    {                                                                             \
      const float* rr = &red[w][row_o][h_o][sub * 16];                            \
      _Pragma("unroll") for (int c = 0; c < 16; ++c) x += rr[c];                  \
    }                                                                             \
    x += __shfl_xor(x, 16);                                                       \
    x += __shfl_xor(x, 32);                                                       \
    if (l < 16) logits[h_o][j0 + (g) * 4 + row_o] = x;                            \
  }

  ISSUE(PA, DA, 0);
  ISSUE(PB, DB, 1);
#pragma unroll
  for (int gg = 0; gg < 8; ++gg) {
    VW(8);
    COMPUTE(PA, DA, 2 * gg);
    if (gg < 7) ISSUE(PA, DA, 2 * gg + 2);
    if (gg < 7) {
      VW(8);
    } else {
      VW(0);
    }
    COMPUTE(PB, DB, 2 * gg + 1);
    if (gg < 7) ISSUE(PB, DB, 2 * gg + 3);
  }
#undef ISSUE
#undef COMPUTE
  __syncthreads();

  // ---- softmax: wave w owns head w; lane l handles j = 4l..4l+3
  float* lrow = &logits[w][0];
  float4 bv = *(float4*)(lrow + 4 * l);
  float v0 = (rowm || m4.x != 0.f) ? -9e15f : qk4.x + bv.x;
  float v1 = (rowm || m4.y != 0.f) ? -9e15f : qk4.y + bv.y;
  float v2 = (rowm || m4.z != 0.f) ? -9e15f : qk4.z + bv.z;
  float v3 = (rowm || m4.w != 0.f) ? -9e15f : qk4.w + bv.w;

  float mx = fmaxf(fmaxf(v0, v1), fmaxf(v2, v3));
#pragma unroll
  for (int m = 1; m <= 32; m <<= 1) mx = fmaxf(mx, __shfl_xor(mx, m));
  float e0 = __expf(v0 - mx), e1 = __expf(v1 - mx);
  float e2 = __expf(v2 - mx), e3 = __expf(v3 - mx);
  float sm = e0 + e1 + e2 + e3;
#pragma unroll
  for (int m = 1; m <= 32; m <<= 1) sm += __shfl_xor(sm, m);
  float inv = 1.0f / sm;
  float4 a4 = make_float4(e0 * inv, e1 * inv, e2 * inv, e3 * inv);
  *(float4*)(qrow + 4 * l) = a4;   // graded attn output
  *(float4*)(lrow + 4 * l) = a4;   // in-LDS for PV (same wave -> no barrier)

  // ---- PV: thread (h=w, l): out-dim l of head w
  float acc = 0.f;
  const float* vbase = vh + (size_t)(b * 4 + w) * 256 * 64 + l;
#pragma unroll 4
  for (int jj = 0; jj < 256; ++jj) acc += lrow[jj] * vbase[(size_t)jj * 64];
  pre[tid] = acc;
  __syncthreads();

  // ---- fc
  float acc2 = fcb[tid];
#pragma unroll 4
  for (int c = 0; c < 256; ++c) acc2 += pre[c] * fcT[(size_t)c * 256 + tid];
  out[(size_t)(b * 256 + i) * 256 + tid] = acc2;
}

// ---------------------------------------------------------------- launcher
extern "C" void kernel_launch(void* const* d_in, const int* in_sizes, int n_in,
                              void* d_out, int out_size, void* d_ws, size_t ws_size,
                              hipStream_t stream) {
  (void)in_sizes; (void)n_in; (void)out_size; (void)ws_size;
  const float* q = (const float*)d_in[0];
  const float* k = (const float*)d_in[1];
  const float* v = (const float*)d_in[2];
  const float* amask = (const float*)d_in[3];
  const unsigned char* kpm = (const unsigned char*)d_in[4];
  const float* pitch = (const float*)d_in[5];
  const float* dur = (const float*)d_in[6];
  const float* Wq = (const float*)d_in[7];
  const float* Bq = (const float*)d_in[8];
  const float* Wk = (const float*)d_in[9];
  const float* Bk = (const float*)d_in[10];
  const float* Wv = (const float*)d_in[11];
  const float* Bv = (const float*)d_in[12];
  const float* fcw = (const float*)d_in[13];
  const float* fcb = (const float*)d_in[14];
  const float* prw = (const float*)d_in[15];
  const float* drw = (const float*)d_in[17];
  // pr_b (16) / dr_b (18) intentionally unused: j-constant logit offsets cancel in softmax.

  float* out = (float*)d_out;
  float* attn = out + 2 * 256 * 256;  // 131072

  float* wsf = (float*)d_ws;
  float* qh = wsf;              // 131072
  float* kh = qh + 131072;      // 131072
  float* vh = kh + 131072;      // 131072
  float* qpr = vh + 131072;     // 524288
  float* qdr = qpr + 524288;    // 524288
  float* fcT = qdr + 524288;    // 65536   (total ~6.03 MB)

  k_proj<<<160, 256, 0, stream>>>(q, k, v, Wq, Bq, Wk, Bk, Wv, Bv, qh, kh, vh, fcw, fcT);
  k_mid<<<384, 256, 0, stream>>>(qh, kh, prw, drw, qpr, qdr, attn);
  k_fused3<<<512, 256, 0, stream>>>(pitch, dur, qpr, qdr, amask, kpm, vh, fcT, fcb, attn, out);
}